// Round 1
// baseline (4592.252 us; speedup 1.0000x reference)
//
#include <hip/hip_runtime.h>
#include <hip/hip_bf16.h>
#include <math.h>

// Problem constants (fixed by setup_inputs)
#define BB 32      // batch
#define TT 12      // encoder steps
#define NN 512     // nodes
#define HH 64      // hidden
#define KK 3       // graph supports
#define DIN 65     // C + H
#define BD 2080    // BB*DIN
#define BDP 2112   // padded to 64*33
#define ROWS 1536  // KK*NN

#define TM 64
#define TN 64
#define TK 32
#define NT 16

// ---------------- pack: XH[j][(b,p)] = concat(x, (r*)h)[b,j,p] ----------------
__global__ __launch_bounds__(256) void pack_xh(const float* __restrict__ xsrc, int xstride_b,
                                               const float* __restrict__ h,
                                               const float* __restrict__ r,  // may be null
                                               float* __restrict__ XH) {
    int idx = blockIdx.x * 256 + threadIdx.x;
    if (idx >= NN * BDP) return;
    int j = idx / BDP;
    int c = idx - j * BDP;
    float v = 0.f;
    if (c < BD) {
        int b = c / DIN;
        int p = c - b * DIN;
        if (p == 0) {
            v = xsrc[b * xstride_b + j];
        } else {
            int q = p - 1;
            int gi = (b * NN + j) * HH + q;
            v = h[gi];
            if (r) v *= r[gi];
        }
    }
    XH[idx] = v;
}

// ---------------- big GEMM: S(1536 x BDP) = Gcat(1536x512) @ XH(512 x BDP) ----------------
__global__ __launch_bounds__(256) void mm_big(const float* __restrict__ A,
                                              const float* __restrict__ Bm,
                                              float* __restrict__ C) {
    __shared__ float As[TK][TM + 4];
    __shared__ float Bs[TK][TN];
    int tid = threadIdx.x;
    int m0 = blockIdx.y * TM;
    int n0 = blockIdx.x * TN;
    int tx = tid & 15, ty = tid >> 4;
    float acc[4][4] = {};
    for (int k0 = 0; k0 < 512; k0 += TK) {
        {
            int rr = tid >> 3;        // 0..31
            int c4 = (tid & 7) * 4;   // 0..28
#pragma unroll
            for (int it = 0; it < 2; ++it) {
                int row = rr + it * 32;
                float4 a = *(const float4*)&A[(size_t)(m0 + row) * 512 + k0 + c4];
                As[c4 + 0][row] = a.x;
                As[c4 + 1][row] = a.y;
                As[c4 + 2][row] = a.z;
                As[c4 + 3][row] = a.w;
            }
        }
        {
            int rr = tid >> 4;        // 0..15
            int c4 = (tid & 15) * 4;  // 0..60
#pragma unroll
            for (int it = 0; it < 2; ++it) {
                int row = rr + it * 16;
                *(float4*)&Bs[row][c4] = *(const float4*)&Bm[(size_t)(k0 + row) * BDP + n0 + c4];
            }
        }
        __syncthreads();
#pragma unroll
        for (int k = 0; k < TK; ++k) {
            float4 av = *(const float4*)&As[k][ty * 4];
            float4 bv = *(const float4*)&Bs[k][tx * 4];
            float a[4] = {av.x, av.y, av.z, av.w};
            float b[4] = {bv.x, bv.y, bv.z, bv.w};
#pragma unroll
            for (int i = 0; i < 4; ++i)
#pragma unroll
                for (int j = 0; j < 4; ++j) acc[i][j] += a[i] * b[j];
        }
        __syncthreads();
    }
#pragma unroll
    for (int i = 0; i < 4; ++i) {
        float4 v = make_float4(acc[i][0], acc[i][1], acc[i][2], acc[i][3]);
        *(float4*)&C[(size_t)(m0 + ty * 4 + i) * BDP + n0 + tx * 4] = v;
    }
}

// ---------------- gates: zr = sigmoid(S . Wg + bg); split into z, r ----------------
__global__ __launch_bounds__(256) void dense_gates(const float* __restrict__ S,
                                                   const float* __restrict__ W,    // 195 x 128
                                                   const float* __restrict__ bias, // 128
                                                   float* __restrict__ z,
                                                   float* __restrict__ r) {
    __shared__ float Sl[NT][200];
    int b = blockIdx.y;
    int n0 = blockIdx.x * NT;
    int tid = threadIdx.x;
    for (int l = tid; l < NT * 195; l += 256) {
        int nn = l / 195;
        int kp = l - nn * 195;
        int k = kp / 65;
        int p = kp - k * 65;
        Sl[nn][kp] = S[(size_t)(k * NN + n0 + nn) * BDP + b * DIN + p];
    }
    __syncthreads();
    int o4 = (tid & 31) * 4;   // 0..124
    int nn = (tid >> 5) * 2;   // 0,2,..,14
    float acc[2][4] = {};
    for (int kp = 0; kp < 195; ++kp) {
        float4 w = *(const float4*)&W[kp * 128 + o4];
        float s0 = Sl[nn][kp], s1 = Sl[nn + 1][kp];
        acc[0][0] += s0 * w.x; acc[0][1] += s0 * w.y; acc[0][2] += s0 * w.z; acc[0][3] += s0 * w.w;
        acc[1][0] += s1 * w.x; acc[1][1] += s1 * w.y; acc[1][2] += s1 * w.z; acc[1][3] += s1 * w.w;
    }
#pragma unroll
    for (int i = 0; i < 2; ++i) {
        int gn = (b * NN + n0 + nn + i) * HH;
#pragma unroll
        for (int j = 0; j < 4; ++j) {
            int o = o4 + j;
            float v = 1.f / (1.f + expf(-(acc[i][j] + bias[o])));
            if (o < HH) z[gn + o] = v;
            else        r[gn + o - HH] = v;
        }
    }
}

// ---------------- candidate + GRU update: h = (1-z)h + z*tanh(S.Wu + bu) ----------------
__global__ __launch_bounds__(256) void dense_cand(const float* __restrict__ S,
                                                  const float* __restrict__ W,    // 195 x 64
                                                  const float* __restrict__ bias, // 64
                                                  const float* __restrict__ z,
                                                  float* __restrict__ h) {
    __shared__ float Sl[NT][200];
    int b = blockIdx.y;
    int n0 = blockIdx.x * NT;
    int tid = threadIdx.x;
    for (int l = tid; l < NT * 195; l += 256) {
        int nn = l / 195;
        int kp = l - nn * 195;
        int k = kp / 65;
        int p = kp - k * 65;
        Sl[nn][kp] = S[(size_t)(k * NN + n0 + nn) * BDP + b * DIN + p];
    }
    __syncthreads();
    int o4 = (tid & 15) * 4;  // 0..60
    int nn = tid >> 4;        // 0..15
    float acc[4] = {};
    for (int kp = 0; kp < 195; ++kp) {
        float4 w = *(const float4*)&W[kp * 64 + o4];
        float s = Sl[nn][kp];
        acc[0] += s * w.x; acc[1] += s * w.y; acc[2] += s * w.z; acc[3] += s * w.w;
    }
    int gn = (b * NN + n0 + nn) * HH;
#pragma unroll
    for (int j = 0; j < 4; ++j) {
        int o = o4 + j;
        float hc = tanhf(acc[j] + bias[o]);
        float zz = z[gn + o];
        float ho = h[gn + o];
        h[gn + o] = (1.f - zz) * ho + zz * hc;
    }
}

// ---------------- decoder projection: go = h @ Wp + bp ; also write output ----------------
__global__ __launch_bounds__(256) void proj(const float* __restrict__ h,
                                            const float* __restrict__ Wp,  // 64 x 1
                                            const float* __restrict__ bp,  // 1
                                            float* __restrict__ go,
                                            float* __restrict__ out, int t, int hor) {
    int idx = blockIdx.x * 256 + threadIdx.x;  // b*NN + n
    if (idx >= BB * NN) return;
    const float* hrow = &h[(size_t)idx * HH];
    float acc = bp[0];
#pragma unroll
    for (int q = 0; q < HH; ++q) acc += hrow[q] * Wp[q];
    go[idx] = acc;
    int b = idx >> 9, n = idx & (NN - 1);
    out[(size_t)(b * hor + t) * NN + n] = acc;
}

extern "C" void kernel_launch(void* const* d_in, const int* in_sizes, int n_in,
                              void* d_out, int out_size, void* d_ws, size_t ws_size,
                              hipStream_t stream) {
    const float* x   = (const float*)d_in[0];
    const float* P   = (const float*)d_in[1];
    const float* Weg = (const float*)d_in[2];
    const float* beg = (const float*)d_in[3];
    const float* Weu = (const float*)d_in[4];
    const float* beu = (const float*)d_in[5];
    const float* Wdg = (const float*)d_in[6];
    const float* bdg = (const float*)d_in[7];
    const float* Wdu = (const float*)d_in[8];
    const float* bdu = (const float*)d_in[9];
    const float* Wp  = (const float*)d_in[10];
    const float* bp  = (const float*)d_in[11];
    float* out = (float*)d_out;
    int hor = out_size / (BB * NN);  // C==1

    float* ws = (float*)d_ws;
    size_t off = 0;
    float* h  = ws + off; off += (size_t)BB * NN * HH;
    float* z  = ws + off; off += (size_t)BB * NN * HH;
    float* r  = ws + off; off += (size_t)BB * NN * HH;
    float* XH = ws + off; off += (size_t)NN * BDP;
    float* S  = ws + off; off += (size_t)ROWS * BDP;
    float* go = ws + off; off += (size_t)BB * NN;

    hipMemsetAsync(h, 0, (size_t)BB * NN * HH * sizeof(float), stream);
    hipMemsetAsync(go, 0, (size_t)BB * NN * sizeof(float), stream);

    dim3 mmgrid(BDP / TN, ROWS / TM);
    dim3 dgrid(NN / NT, BB);
    int packblocks = (NN * BDP) / 256;

    // encoder
    for (int t = 0; t < TT; ++t) {
        const float* xb = x + (size_t)t * NN;  // x[b,t,n,0], b-stride TT*NN
        pack_xh<<<packblocks, 256, 0, stream>>>(xb, TT * NN, h, nullptr, XH);
        mm_big<<<mmgrid, 256, 0, stream>>>(P, XH, S);
        dense_gates<<<dgrid, 256, 0, stream>>>(S, Weg, beg, z, r);
        pack_xh<<<packblocks, 256, 0, stream>>>(xb, TT * NN, h, r, XH);
        mm_big<<<mmgrid, 256, 0, stream>>>(P, XH, S);
        dense_cand<<<dgrid, 256, 0, stream>>>(S, Weu, beu, z, h);
    }
    // decoder
    for (int t = 0; t < hor; ++t) {
        pack_xh<<<packblocks, 256, 0, stream>>>(go, NN, h, nullptr, XH);
        mm_big<<<mmgrid, 256, 0, stream>>>(P, XH, S);
        dense_gates<<<dgrid, 256, 0, stream>>>(S, Wdg, bdg, z, r);
        pack_xh<<<packblocks, 256, 0, stream>>>(go, NN, h, r, XH);
        mm_big<<<mmgrid, 256, 0, stream>>>(P, XH, S);
        dense_cand<<<dgrid, 256, 0, stream>>>(S, Wdu, bdu, z, h);
        proj<<<(BB * NN) / 256, 256, 0, stream>>>(h, Wp, bp, go, out, t, hor);
    }
}

// Round 2
// 2273.100 us; speedup vs baseline: 2.0203x; 2.0203x over previous
//
#include <hip/hip_runtime.h>
#include <hip/hip_bf16.h>
#include <math.h>

// Problem constants (fixed by setup_inputs)
#define BB 32      // batch
#define TT 12      // encoder steps
#define NN 512     // nodes
#define HH 64      // hidden
#define KK 3       // graph supports
#define DIN 65     // C + H
#define BD 2080    // BB*DIN
#define BDP 2112   // padded cols = 132*16
#define ROWS 1536  // KK*NN
#define NSUB 132   // BDP/16 n-subtiles
#define MSUB 96    // ROWS/16 m-subtiles
#define KSTEPS 16  // 512/32

#define NT 16

typedef _Float16 f16;
typedef f16 f16x8 __attribute__((ext_vector_type(8)));
typedef float f32x4 __attribute__((ext_vector_type(4)));

#define GLD_LDS16(g, l) \
    __builtin_amdgcn_global_load_lds((const __attribute__((address_space(1))) void*)(g), \
                                     (__attribute__((address_space(3))) void*)(l), 16, 0, 0)

// ---------------- convert P (f32, 1536x512 row-major) -> fragment-major f16 ----------------
// layout: slot u = (ks*MSUB + ms)*64 + lane; elements k = ks*32 + (lane>>4)*8 + i, m = ms*16 + (lane&15)
__global__ __launch_bounds__(256) void conv_a(const float* __restrict__ P, f16* __restrict__ Af) {
    int u = blockIdx.x * 256 + threadIdx.x;  // 0 .. 1536*512/8-1
    int lane = u & 63;
    int su = u >> 6;
    int ks = su / MSUB, ms = su - ks * MSUB;
    int m = ms * 16 + (lane & 15);
    int k = ks * 32 + (lane >> 4) * 8;
    const float* src = &P[(size_t)m * 512 + k];
    f16x8 v;
#pragma unroll
    for (int i = 0; i < 8; ++i) v[i] = (f16)src[i];
    *(f16x8*)&Af[(size_t)u * 8] = v;
}

// ---------------- pack XH into fragment-major f16 B operand ----------------
// slot u = (ks*NSUB + ns)*64 + lane; k(=j) = ks*32 + (lane>>4)*8 + i, col c = ns*16 + (lane&15)
__global__ __launch_bounds__(256) void pack_frag(const float* __restrict__ xsrc, int xstride_b,
                                                 const float* __restrict__ h,
                                                 const float* __restrict__ r,  // may be null
                                                 f16* __restrict__ Bf) {
    int u = blockIdx.x * 256 + threadIdx.x;  // 0 .. 512*2112/8-1
    int lane = u & 63;
    int su = u >> 6;
    int ks = su / NSUB, ns = su - ks * NSUB;
    int c = ns * 16 + (lane & 15);
    int j0 = ks * 32 + (lane >> 4) * 8;
    f16x8 v = {};
    if (c < BD) {
        int b = c / DIN, p = c - b * DIN;
        if (p == 0) {
            const float* xp = &xsrc[(size_t)b * xstride_b + j0];
#pragma unroll
            for (int i = 0; i < 8; ++i) v[i] = (f16)xp[i];
        } else {
            int q = p - 1;
            const float* hp = &h[((size_t)b * NN + j0) * HH + q];
            if (r) {
                const float* rp = &r[((size_t)b * NN + j0) * HH + q];
#pragma unroll
                for (int i = 0; i < 8; ++i) v[i] = (f16)(hp[i * HH] * rp[i * HH]);
            } else {
#pragma unroll
                for (int i = 0; i < 8; ++i) v[i] = (f16)hp[i * HH];
            }
        }
    }
    *(f16x8*)&Bf[(size_t)u * 8] = v;
}

// ---------------- MFMA GEMM: S(f32, 1536 x 2112) = Af(1536x512) @ Bf(512x2112), f16 in, f32 acc ----
// 64x64 tile, 4 waves, wave = 32x32 (2x2 fragments), K-step 32, double-buffered LDS.
__global__ __launch_bounds__(256) void mm_f16(const f16* __restrict__ Af,
                                              const f16* __restrict__ Bf,
                                              float* __restrict__ C) {
    __shared__ f16 lds[8192];  // [2 bufs][A 2048 | B 2048] f16 elems = 16 KB
    int tid = threadIdx.x, wave = tid >> 6, lane = tid & 63;
    int nb = blockIdx.x, mb = blockIdx.y;

    int mi0 = (wave & 1) * 2;   // wave's m-subtile base (of 4 in block)
    int nj0 = (wave >> 1) * 2;  // wave's n-subtile base
    f32x4 acc[2][2] = {};

#define STAGE(d, ks)                                                                  \
    do {                                                                              \
        const f16* ga = &Af[((size_t)((ks)*MSUB + mb * 4) * 64 + tid) * 8];           \
        const f16* gb = &Bf[((size_t)((ks)*NSUB + nb * 4) * 64 + tid) * 8];           \
        f16* la = &lds[(d)*4096 + wave * 512];                                        \
        f16* lb = &lds[(d)*4096 + 2048 + wave * 512];                                 \
        GLD_LDS16(ga, la);                                                            \
        GLD_LDS16(gb, lb);                                                            \
    } while (0)

    STAGE(0, 0);
#pragma unroll 1
    for (int ks = 0; ks < KSTEPS; ++ks) {
        int d = ks & 1;
        __syncthreads();  // staging for ks visible (vmcnt drained); prior-buf reads done
        if (ks + 1 < KSTEPS) STAGE(d ^ 1, ks + 1);
        f16x8 af[2], bf[2];
#pragma unroll
        for (int a = 0; a < 2; ++a) af[a] = *(const f16x8*)&lds[d * 4096 + (mi0 + a) * 512 + lane * 8];
#pragma unroll
        for (int b = 0; b < 2; ++b) bf[b] = *(const f16x8*)&lds[d * 4096 + 2048 + (nj0 + b) * 512 + lane * 8];
#pragma unroll
        for (int a = 0; a < 2; ++a)
#pragma unroll
            for (int b = 0; b < 2; ++b)
                acc[a][b] = __builtin_amdgcn_mfma_f32_16x16x32_f16(af[a], bf[b], acc[a][b], 0, 0, 0);
    }
#undef STAGE

    int m0 = mb * 64, n0 = nb * 64;
    int row_l = (lane >> 4) * 4, col_l = lane & 15;
#pragma unroll
    for (int a = 0; a < 2; ++a)
#pragma unroll
        for (int b = 0; b < 2; ++b) {
            int rbase = m0 + (mi0 + a) * 16 + row_l;
            int cc = n0 + (nj0 + b) * 16 + col_l;
#pragma unroll
            for (int rI = 0; rI < 4; ++rI)
                C[(size_t)(rbase + rI) * BDP + cc] = acc[a][b][rI];
        }
}

// ---------------- gates: zr = sigmoid(S . Wg + bg); split into z, r ----------------
__global__ __launch_bounds__(256) void dense_gates(const float* __restrict__ S,
                                                   const float* __restrict__ W,    // 195 x 128
                                                   const float* __restrict__ bias, // 128
                                                   float* __restrict__ z,
                                                   float* __restrict__ r) {
    __shared__ float Sl[NT][200];
    int b = blockIdx.y;
    int n0 = blockIdx.x * NT;
    int tid = threadIdx.x;
    for (int l = tid; l < NT * 195; l += 256) {
        int nn = l / 195;
        int kp = l - nn * 195;
        int k = kp / 65;
        int p = kp - k * 65;
        Sl[nn][kp] = S[(size_t)(k * NN + n0 + nn) * BDP + b * DIN + p];
    }
    __syncthreads();
    int o4 = (tid & 31) * 4;   // 0..124
    int nn = (tid >> 5) * 2;   // 0,2,..,14
    float acc[2][4] = {};
    for (int kp = 0; kp < 195; ++kp) {
        float4 w = *(const float4*)&W[kp * 128 + o4];
        float s0 = Sl[nn][kp], s1 = Sl[nn + 1][kp];
        acc[0][0] += s0 * w.x; acc[0][1] += s0 * w.y; acc[0][2] += s0 * w.z; acc[0][3] += s0 * w.w;
        acc[1][0] += s1 * w.x; acc[1][1] += s1 * w.y; acc[1][2] += s1 * w.z; acc[1][3] += s1 * w.w;
    }
#pragma unroll
    for (int i = 0; i < 2; ++i) {
        int gn = (b * NN + n0 + nn + i) * HH;
#pragma unroll
        for (int j = 0; j < 4; ++j) {
            int o = o4 + j;
            float v = 1.f / (1.f + expf(-(acc[i][j] + bias[o])));
            if (o < HH) z[gn + o] = v;
            else        r[gn + o - HH] = v;
        }
    }
}

// ---------------- candidate + GRU update: h = (1-z)h + z*tanh(S.Wu + bu) ----------------
__global__ __launch_bounds__(256) void dense_cand(const float* __restrict__ S,
                                                  const float* __restrict__ W,    // 195 x 64
                                                  const float* __restrict__ bias, // 64
                                                  const float* __restrict__ z,
                                                  float* __restrict__ h) {
    __shared__ float Sl[NT][200];
    int b = blockIdx.y;
    int n0 = blockIdx.x * NT;
    int tid = threadIdx.x;
    for (int l = tid; l < NT * 195; l += 256) {
        int nn = l / 195;
        int kp = l - nn * 195;
        int k = kp / 65;
        int p = kp - k * 65;
        Sl[nn][kp] = S[(size_t)(k * NN + n0 + nn) * BDP + b * DIN + p];
    }
    __syncthreads();
    int o4 = (tid & 15) * 4;  // 0..60
    int nn = tid >> 4;        // 0..15
    float acc[4] = {};
    for (int kp = 0; kp < 195; ++kp) {
        float4 w = *(const float4*)&W[kp * 64 + o4];
        float s = Sl[nn][kp];
        acc[0] += s * w.x; acc[1] += s * w.y; acc[2] += s * w.z; acc[3] += s * w.w;
    }
    int gn = (b * NN + n0 + nn) * HH;
#pragma unroll
    for (int j = 0; j < 4; ++j) {
        int o = o4 + j;
        float hc = tanhf(acc[j] + bias[o]);
        float zz = z[gn + o];
        float ho = h[gn + o];
        h[gn + o] = (1.f - zz) * ho + zz * hc;
    }
}

// ---------------- decoder projection: go = h @ Wp + bp ; also write output ----------------
__global__ __launch_bounds__(256) void proj(const float* __restrict__ h,
                                            const float* __restrict__ Wp,  // 64 x 1
                                            const float* __restrict__ bp,  // 1
                                            float* __restrict__ go,
                                            float* __restrict__ out, int t, int hor) {
    int idx = blockIdx.x * 256 + threadIdx.x;  // b*NN + n
    if (idx >= BB * NN) return;
    const float* hrow = &h[(size_t)idx * HH];
    float acc = bp[0];
#pragma unroll
    for (int q = 0; q < HH; ++q) acc += hrow[q] * Wp[q];
    go[idx] = acc;
    int b = idx >> 9, n = idx & (NN - 1);
    out[(size_t)(b * hor + t) * NN + n] = acc;
}

extern "C" void kernel_launch(void* const* d_in, const int* in_sizes, int n_in,
                              void* d_out, int out_size, void* d_ws, size_t ws_size,
                              hipStream_t stream) {
    const float* x   = (const float*)d_in[0];
    const float* P   = (const float*)d_in[1];
    const float* Weg = (const float*)d_in[2];
    const float* beg = (const float*)d_in[3];
    const float* Weu = (const float*)d_in[4];
    const float* beu = (const float*)d_in[5];
    const float* Wdg = (const float*)d_in[6];
    const float* bdg = (const float*)d_in[7];
    const float* Wdu = (const float*)d_in[8];
    const float* bdu = (const float*)d_in[9];
    const float* Wp  = (const float*)d_in[10];
    const float* bp  = (const float*)d_in[11];
    float* out = (float*)d_out;
    int hor = out_size / (BB * NN);  // C==1

    float* ws = (float*)d_ws;
    size_t off = 0;
    float* h  = ws + off; off += (size_t)BB * NN * HH;        // 1048576
    float* z  = ws + off; off += (size_t)BB * NN * HH;
    float* r  = ws + off; off += (size_t)BB * NN * HH;
    float* S  = ws + off; off += (size_t)ROWS * BDP;          // 3244032
    float* go = ws + off; off += (size_t)BB * NN;             // 16384
    f16*  Af  = (f16*)(ws + off); off += (size_t)ROWS * 512 / 2;     // 1536*512 f16
    f16*  Bf  = (f16*)(ws + off); off += (size_t)512 * BDP / 2;      // 512*2112 f16

    hipMemsetAsync(h, 0, (size_t)BB * NN * HH * sizeof(float), stream);
    hipMemsetAsync(go, 0, (size_t)BB * NN * sizeof(float), stream);

    conv_a<<<(ROWS * 512 / 8) / 256, 256, 0, stream>>>(P, Af);

    dim3 mmgrid(BDP / 64, ROWS / 64);  // 33 x 24
    dim3 dgrid(NN / NT, BB);
    int packblocks = (512 * BDP / 8) / 256;  // 528

    // encoder
    for (int t = 0; t < TT; ++t) {
        const float* xb = x + (size_t)t * NN;  // x[b,t,n,0], b-stride TT*NN
        pack_frag<<<packblocks, 256, 0, stream>>>(xb, TT * NN, h, nullptr, Bf);
        mm_f16<<<mmgrid, 256, 0, stream>>>(Af, Bf, S);
        dense_gates<<<dgrid, 256, 0, stream>>>(S, Weg, beg, z, r);
        pack_frag<<<packblocks, 256, 0, stream>>>(xb, TT * NN, h, r, Bf);
        mm_f16<<<mmgrid, 256, 0, stream>>>(Af, Bf, S);
        dense_cand<<<dgrid, 256, 0, stream>>>(S, Weu, beu, z, h);
    }
    // decoder
    for (int t = 0; t < hor; ++t) {
        pack_frag<<<packblocks, 256, 0, stream>>>(go, NN, h, nullptr, Bf);
        mm_f16<<<mmgrid, 256, 0, stream>>>(Af, Bf, S);
        dense_gates<<<dgrid, 256, 0, stream>>>(S, Wdg, bdg, z, r);
        pack_frag<<<packblocks, 256, 0, stream>>>(go, NN, h, r, Bf);
        mm_f16<<<mmgrid, 256, 0, stream>>>(Af, Bf, S);
        dense_cand<<<dgrid, 256, 0, stream>>>(S, Wdu, bdu, z, h);
        proj<<<(BB * NN) / 256, 256, 0, stream>>>(h, Wp, bp, go, out, t, hor);
    }
}

// Round 4
// 1010.144 us; speedup vs baseline: 4.5461x; 2.2503x over previous
//
#include <hip/hip_runtime.h>
#include <hip/hip_bf16.h>
#include <math.h>

// Problem constants
#define BB 32
#define TT 12
#define NN 512
#define HH 64
#define KK 3
#define DIN 65
#define BD 2080        // BB*DIN valid cols
#define BDP 2176       // padded cols = 17*128
#define ROWS 1536      // KK*NN
#define NSUB 136       // BDP/16
#define MSUB 96        // ROWS/16
#define RTOT 16384     // BB*NN dense rows
#define KP 224         // dense K padded (195 -> 7*32)

typedef _Float16 f16;
typedef f16 f16x8 __attribute__((ext_vector_type(8)));
typedef float f32x4 __attribute__((ext_vector_type(4)));

#define GLD_LDS16(g, l) \
    __builtin_amdgcn_global_load_lds((const __attribute__((address_space(1))) void*)(g), \
                                     (__attribute__((address_space(3))) void*)(l), 16, 0, 0)

// Bf fragment address for element (node j, col c), in f16 units
__device__ __forceinline__ int bf_addr(int j, int c) {
    return (((j >> 5) * NSUB + (c >> 4)) * 64 + ((j >> 3) & 3) * 16 + (c & 15)) * 8 + (j & 7);
}

// ---------------- convert P (f32, 1536x512 row-major) -> fragment-major f16 A ----------------
__global__ __launch_bounds__(256) void conv_a(const float* __restrict__ P, f16* __restrict__ Af) {
    int u = blockIdx.x * 256 + threadIdx.x;  // 1536*512/8 slots
    int lane = u & 63;
    int su = u >> 6;
    int ks = su / MSUB, ms = su - ks * MSUB;
    int m = ms * 16 + (lane & 15);
    int k = ks * 32 + (lane >> 4) * 8;
    const float* src = &P[(size_t)m * 512 + k];
    f16x8 v;
#pragma unroll
    for (int i = 0; i < 8; ++i) v[i] = (f16)src[i];
    *(f16x8*)&Af[(size_t)u * 8] = v;
}

// ---------------- convert dense weight (195 x O f32) -> fragment-major f16, K padded to 224 ----
__global__ __launch_bounds__(256) void conv_w(const float* __restrict__ W, int O, int OS,
                                              f16* __restrict__ Wf) {
    int u = blockIdx.x * 256 + threadIdx.x;
    if (u >= 7 * OS * 64) return;
    int lane = u & 63;
    int su = u >> 6;
    int ks = su / OS, os = su - ks * OS;
    int o = os * 16 + (lane & 15);
    int k0 = ks * 32 + (lane >> 4) * 8;
    f16x8 v;
#pragma unroll
    for (int i = 0; i < 8; ++i) {
        int kk = k0 + i;
        v[i] = (kk < 195) ? (f16)W[kk * O + o] : (f16)0.f;
    }
    *(f16x8*)&Wf[(size_t)u * 8] = v;
}

// ---------------- update Bf x-columns (p=0): from x[b,t,:,0] (or zero if x==null) -------------
__global__ __launch_bounds__(256) void upd_x(const float* __restrict__ x, int t,
                                             f16* __restrict__ Bf) {
    int idx = blockIdx.x * 256 + threadIdx.x;  // R = b*512+n
    if (idx >= RTOT) return;
    int b = idx >> 9, n = idx & 511;
    float v = x ? x[((size_t)b * TT + t) * NN + n] : 0.f;
    Bf[bf_addr(n, b * DIN)] = (f16)v;
}

// ---------------- big MFMA GEMM: S_t = (Af @ Bf) stored as f16 [(b,n)][k*65+p], stride 256 ----
// 128x128 tile, BK=64, 4 waves (2x2), wave = 64x64 = 4x4 frags of 16x16x32.
__global__ __launch_bounds__(256) void mm_f16(const f16* __restrict__ Af,
                                              const f16* __restrict__ Bf,
                                              f16* __restrict__ St) {
    __shared__ f16 lds[2][16384];  // per buf: A 8192 f16 | B 8192 f16 (32 KB)
    int tid = threadIdx.x, wave = tid >> 6, lane = tid & 63;
    int wr = wave & 1, wc = wave >> 1;
    int mb = blockIdx.y, nb = blockIdx.x;
    f32x4 acc[4][4] = {};

#define STG(d, it)                                                                           \
    do {                                                                                     \
        int ks0 = (it) * 2;                                                                  \
        _Pragma("unroll") for (int q = 0; q < 4; ++q) {                                      \
            int s = q * 4 + wave;                                                            \
            int ksl = s >> 3, sub = s & 7;                                                   \
            GLD_LDS16(&Af[((size_t)((ks0 + ksl) * MSUB + mb * 8 + sub) * 64 + lane) * 8],    \
                      &lds[d][s * 512 + lane * 8]);                                          \
            GLD_LDS16(&Bf[((size_t)((ks0 + ksl) * NSUB + nb * 8 + sub) * 64 + lane) * 8],    \
                      &lds[d][8192 + s * 512 + lane * 8]);                                   \
        }                                                                                    \
    } while (0)

    STG(0, 0);
#pragma unroll 1
    for (int it = 0; it < 8; ++it) {
        int d = it & 1;
        __syncthreads();
        if (it + 1 < 8) STG(d ^ 1, it + 1);
#pragma unroll
        for (int kk = 0; kk < 2; ++kk) {
            f16x8 a[4], b[4];
#pragma unroll
            for (int i = 0; i < 4; ++i) a[i] = *(const f16x8*)&lds[d][(kk * 8 + wr * 4 + i) * 512 + lane * 8];
#pragma unroll
            for (int j = 0; j < 4; ++j) b[j] = *(const f16x8*)&lds[d][8192 + (kk * 8 + wc * 4 + j) * 512 + lane * 8];
#pragma unroll
            for (int i = 0; i < 4; ++i)
#pragma unroll
                for (int j = 0; j < 4; ++j)
                    acc[i][j] = __builtin_amdgcn_mfma_f32_16x16x32_f16(a[i], b[j], acc[i][j], 0, 0, 0);
        }
    }
#undef STG

    // epilogue: element (m, c) -> S_t[(b*512+n)*256 + k*65+p] f16
    int k = (mb * 128) >> 9;  // constant per block
    int col = lane & 15;
#pragma unroll
    for (int j = 0; j < 4; ++j) {
        int c = nb * 128 + (wc * 4 + j) * 16 + col;
        if (c < BD) {
            int b = c / DIN, p = c - b * DIN;
            size_t base = (size_t)(b * 512) * 256 + k * DIN + p;
#pragma unroll
            for (int i = 0; i < 4; ++i) {
                int n0 = (mb * 8 + wr * 4 + i) * 16 + (lane >> 4) * 4 - k * 512;
#pragma unroll
                for (int rI = 0; rI < 4; ++rI)
                    St[base + (size_t)(n0 + rI) * 256] = (f16)acc[i][j][rI];
            }
        }
    }
}

// ---------------- gates dense: zr = sigmoid(S_t @ Wg + bg); z->zf frags, r*h -> Bf ------------
// M=16384, N=128, K=224. Block: 64 rows, 4 waves 2x2, wave = 32R x 64o.
__global__ __launch_bounds__(256) void dense_gates(const f16* __restrict__ St,
                                                   const f16* __restrict__ Wf,
                                                   const float* __restrict__ bias,
                                                   const float* __restrict__ hf,
                                                   float* __restrict__ zf,
                                                   f16* __restrict__ Bf) {
    int tid = threadIdx.x, wave = tid >> 6, lane = tid & 63;
    int wr = wave & 1, wc = wave >> 1;
    int R0 = blockIdx.x * 64 + wr * 32;

    f16x8 af[7][2];
    const f16* Sb = St + (size_t)(R0 + (lane & 15)) * 256 + (lane >> 4) * 8;
#pragma unroll
    for (int ks = 0; ks < 7; ++ks)
#pragma unroll
        for (int rs = 0; rs < 2; ++rs)
            af[ks][rs] = *(const f16x8*)&Sb[(size_t)rs * 16 * 256 + ks * 32];

    f32x4 acc[2][4] = {};
#pragma unroll
    for (int ks = 0; ks < 7; ++ks)
#pragma unroll
        for (int os = 0; os < 4; ++os) {
            f16x8 w = *(const f16x8*)&Wf[((size_t)(ks * 8 + wc * 4 + os) * 64 + lane) * 8];
#pragma unroll
            for (int rs = 0; rs < 2; ++rs)
                acc[rs][os] = __builtin_amdgcn_mfma_f32_16x16x32_f16(af[ks][rs], w, acc[rs][os], 0, 0, 0);
        }

    int col = lane & 15;
#pragma unroll
    for (int rs = 0; rs < 2; ++rs) {
        int rf = (R0 >> 4) + rs;
#pragma unroll
        for (int os = 0; os < 4; ++os) {
            int o = wc * 64 + os * 16 + col;
            float bs = bias[o];
            if (wc == 0) {
                f32x4 v;
#pragma unroll
                for (int rI = 0; rI < 4; ++rI) v[rI] = 1.f / (1.f + expf(-(acc[rs][os][rI] + bs)));
                *(f32x4*)&zf[((size_t)(rf * 4 + os) * 64 + lane) * 4] = v;
            } else {
                int oh = o - 64;
                f32x4 hv = *(const f32x4*)&hf[((size_t)(rf * 4 + os) * 64 + lane) * 4];
#pragma unroll
                for (int rI = 0; rI < 4; ++rI) {
                    float rr = 1.f / (1.f + expf(-(acc[rs][os][rI] + bs)));
                    int R = rf * 16 + (lane >> 4) * 4 + rI;
                    int n = R & 511, b = R >> 9;
                    Bf[bf_addr(n, b * DIN + 1 + oh)] = (f16)(rr * hv[rI]);
                }
            }
        }
    }
}

// ---------------- candidate dense + GRU update: h = (1-z)h + z*tanh(S_t @ Wu + bu) ------------
// M=16384, N=64. Block: 64 rows, 4 waves 2x2, wave = 32R x 32o.
__global__ __launch_bounds__(256) void dense_cand(const f16* __restrict__ St,
                                                  const f16* __restrict__ Wf,
                                                  const float* __restrict__ bias,
                                                  const float* __restrict__ zf,
                                                  float* __restrict__ hf,
                                                  f16* __restrict__ Bf) {
    int tid = threadIdx.x, wave = tid >> 6, lane = tid & 63;
    int wr = wave & 1, wc = wave >> 1;
    int R0 = blockIdx.x * 64 + wr * 32;

    f16x8 af[7][2];
    const f16* Sb = St + (size_t)(R0 + (lane & 15)) * 256 + (lane >> 4) * 8;
#pragma unroll
    for (int ks = 0; ks < 7; ++ks)
#pragma unroll
        for (int rs = 0; rs < 2; ++rs)
            af[ks][rs] = *(const f16x8*)&Sb[(size_t)rs * 16 * 256 + ks * 32];

    f32x4 acc[2][2] = {};
#pragma unroll
    for (int ks = 0; ks < 7; ++ks)
#pragma unroll
        for (int os = 0; os < 2; ++os) {
            f16x8 w = *(const f16x8*)&Wf[((size_t)(ks * 4 + wc * 2 + os) * 64 + lane) * 8];
#pragma unroll
            for (int rs = 0; rs < 2; ++rs)
                acc[rs][os] = __builtin_amdgcn_mfma_f32_16x16x32_f16(af[ks][rs], w, acc[rs][os], 0, 0, 0);
        }

    int col = lane & 15;
#pragma unroll
    for (int rs = 0; rs < 2; ++rs) {
        int rf = (R0 >> 4) + rs;
#pragma unroll
        for (int os = 0; os < 2; ++os) {
            int o = wc * 32 + os * 16 + col;
            int of = wc * 2 + os;
            float bs = bias[o];
            f32x4 zv = *(const f32x4*)&zf[((size_t)(rf * 4 + of) * 64 + lane) * 4];
            f32x4 hv = *(const f32x4*)&hf[((size_t)(rf * 4 + of) * 64 + lane) * 4];
            f32x4 hn;
#pragma unroll
            for (int rI = 0; rI < 4; ++rI) {
                float hc = tanhf(acc[rs][os][rI] + bs);
                hn[rI] = (1.f - zv[rI]) * hv[rI] + zv[rI] * hc;
            }
            *(f32x4*)&hf[((size_t)(rf * 4 + of) * 64 + lane) * 4] = hn;
#pragma unroll
            for (int rI = 0; rI < 4; ++rI) {
                int R = rf * 16 + (lane >> 4) * 4 + rI;
                int n = R & 511, b = R >> 9;
                Bf[bf_addr(n, b * DIN + 1 + o)] = (f16)hn[rI];
            }
        }
    }
}

// ---------------- decoder projection: go = h @ Wp + bp -> out and Bf x-col --------------------
// One wave per 16-row fragment rf; grid must cover rf = 0..RTOT/16-1.
__global__ __launch_bounds__(256) void proj(const float* __restrict__ hf,
                                            const float* __restrict__ Wp,
                                            const float* __restrict__ bp,
                                            f16* __restrict__ Bf,
                                            float* __restrict__ out, int t, int hor) {
    int tid = threadIdx.x, wave = tid >> 6, lane = tid & 63;
    int rf = blockIdx.x * 4 + wave;  // 0..1023
    float p[4] = {0.f, 0.f, 0.f, 0.f};
#pragma unroll
    for (int of = 0; of < 4; ++of) {
        f32x4 hv = *(const f32x4*)&hf[((size_t)(rf * 4 + of) * 64 + lane) * 4];
        float w = Wp[of * 16 + (lane & 15)];
#pragma unroll
        for (int rI = 0; rI < 4; ++rI) p[rI] += hv[rI] * w;
    }
#pragma unroll
    for (int m = 1; m < 16; m <<= 1)
#pragma unroll
        for (int rI = 0; rI < 4; ++rI) p[rI] += __shfl_xor(p[rI], m, 64);
    int q = lane & 15;
    if (q < 4) {
        float val = p[q] + bp[0];
        int R = rf * 16 + (lane >> 4) * 4 + q;
        int n = R & 511, b = R >> 9;
        out[((size_t)b * hor + t) * NN + n] = val;
        Bf[bf_addr(n, b * DIN)] = (f16)val;
    }
}

extern "C" void kernel_launch(void* const* d_in, const int* in_sizes, int n_in,
                              void* d_out, int out_size, void* d_ws, size_t ws_size,
                              hipStream_t stream) {
    const float* x   = (const float*)d_in[0];
    const float* P   = (const float*)d_in[1];
    const float* Weg = (const float*)d_in[2];
    const float* beg = (const float*)d_in[3];
    const float* Weu = (const float*)d_in[4];
    const float* beu = (const float*)d_in[5];
    const float* Wdg = (const float*)d_in[6];
    const float* bdg = (const float*)d_in[7];
    const float* Wdu = (const float*)d_in[8];
    const float* bdu = (const float*)d_in[9];
    const float* Wp  = (const float*)d_in[10];
    const float* bp  = (const float*)d_in[11];
    float* out = (float*)d_out;
    int hor = out_size / (BB * NN);

    float* ws = (float*)d_ws;
    size_t off = 0;
    float* hf = ws + off; off += (size_t)RTOT * HH;                 // frag-major h (4 MB)
    float* zf = ws + off; off += (size_t)RTOT * HH;                 // frag-major z (4 MB)
    f16* St   = (f16*)(ws + off); off += (size_t)RTOT * 256 / 2;    // S_t f16 [16384][256]
    f16* Bf   = (f16*)(ws + off); off += (size_t)512 * BDP / 2;     // B frag-major
    f16* Af   = (f16*)(ws + off); off += (size_t)ROWS * 512 / 2;    // A frag-major
    f16* Wfeg = (f16*)(ws + off); off += 7 * 8 * 64 * 8 / 2;
    f16* Wfeu = (f16*)(ws + off); off += 7 * 4 * 64 * 8 / 2;
    f16* Wfdg = (f16*)(ws + off); off += 7 * 8 * 64 * 8 / 2;
    f16* Wfdu = (f16*)(ws + off); off += 7 * 4 * 64 * 8 / 2;

    hipMemsetAsync(hf, 0, (size_t)RTOT * HH * sizeof(float), stream);
    hipMemsetAsync(Bf, 0, (size_t)512 * BDP * sizeof(f16), stream);
    hipMemsetAsync(St, 0, (size_t)RTOT * 256 * sizeof(f16), stream);  // k-pad cols must be finite

    conv_a<<<(ROWS * 512 / 8) / 256, 256, 0, stream>>>(P, Af);
    conv_w<<<14, 256, 0, stream>>>(Weg, 128, 8, Wfeg);
    conv_w<<<7,  256, 0, stream>>>(Weu, 64, 4, Wfeu);
    conv_w<<<14, 256, 0, stream>>>(Wdg, 128, 8, Wfdg);
    conv_w<<<7,  256, 0, stream>>>(Wdu, 64, 4, Wfdu);

    dim3 mmgrid(BDP / 128, ROWS / 128);  // 17 x 12

    for (int t = 0; t < TT; ++t) {
        upd_x<<<RTOT / 256, 256, 0, stream>>>(x, t, Bf);
        mm_f16<<<mmgrid, 256, 0, stream>>>(Af, Bf, St);
        dense_gates<<<RTOT / 64, 256, 0, stream>>>(St, Wfeg, beg, hf, zf, Bf);
        mm_f16<<<mmgrid, 256, 0, stream>>>(Af, Bf, St);
        dense_cand<<<RTOT / 64, 256, 0, stream>>>(St, Wfeu, beu, zf, hf, Bf);
    }
    upd_x<<<RTOT / 256, 256, 0, stream>>>(nullptr, 0, Bf);  // go0 = 0
    for (int t = 0; t < hor; ++t) {
        mm_f16<<<mmgrid, 256, 0, stream>>>(Af, Bf, St);
        dense_gates<<<RTOT / 64, 256, 0, stream>>>(St, Wfdg, bdg, hf, zf, Bf);
        mm_f16<<<mmgrid, 256, 0, stream>>>(Af, Bf, St);
        dense_cand<<<RTOT / 64, 256, 0, stream>>>(St, Wfdu, bdu, zf, hf, Bf);
        proj<<<RTOT / 16 / 4, 256, 0, stream>>>(hf, Wp, bp, Bf, out, t, hor);
    }
}

// Round 5
// 949.034 us; speedup vs baseline: 4.8389x; 1.0644x over previous
//
#include <hip/hip_runtime.h>
#include <hip/hip_bf16.h>
#include <math.h>

// Problem constants
#define BB 32
#define TT 12
#define NN 512
#define HH 64
#define KK 3
#define DIN 65
#define BD 2080        // BB*DIN valid cols
#define BDP 2176       // padded cols = 17*128
#define ROWS 1536      // KK*NN
#define NSUB 136       // BDP/16
#define MSUB 96        // ROWS/16
#define RTOT 16384     // BB*NN dense rows
#define KP 224         // dense K padded (195 -> 7*32)

typedef _Float16 f16;
typedef f16 f16x8 __attribute__((ext_vector_type(8)));
typedef float f32x4 __attribute__((ext_vector_type(4)));

#define GLD_LDS16(g, l) \
    __builtin_amdgcn_global_load_lds((const __attribute__((address_space(1))) void*)(g), \
                                     (__attribute__((address_space(3))) void*)(l), 16, 0, 0)

// Bf fragment address for element (node j, col c), in f16 units
__device__ __forceinline__ int bf_addr(int j, int c) {
    return (((j >> 5) * NSUB + (c >> 4)) * 64 + ((j >> 3) & 3) * 16 + (c & 15)) * 8 + (j & 7);
}

// ---------------- convert P (f32, 1536x512 row-major) -> fragment-major f16 A ----------------
__global__ __launch_bounds__(256) void conv_a(const float* __restrict__ P, f16* __restrict__ Af) {
    int u = blockIdx.x * 256 + threadIdx.x;  // 1536*512/8 slots
    int lane = u & 63;
    int su = u >> 6;
    int ks = su / MSUB, ms = su - ks * MSUB;
    int m = ms * 16 + (lane & 15);
    int k = ks * 32 + (lane >> 4) * 8;
    const float* src = &P[(size_t)m * 512 + k];
    f16x8 v;
#pragma unroll
    for (int i = 0; i < 8; ++i) v[i] = (f16)src[i];
    *(f16x8*)&Af[(size_t)u * 8] = v;
}

// ---------------- convert dense weight (195 x O f32) -> fragment-major f16, K padded to 224 ----
__global__ __launch_bounds__(256) void conv_w(const float* __restrict__ W, int O, int OS,
                                              f16* __restrict__ Wf) {
    int u = blockIdx.x * 256 + threadIdx.x;
    if (u >= 7 * OS * 64) return;
    int lane = u & 63;
    int su = u >> 6;
    int ks = su / OS, os = su - ks * OS;
    int o = os * 16 + (lane & 15);
    int k0 = ks * 32 + (lane >> 4) * 8;
    f16x8 v;
#pragma unroll
    for (int i = 0; i < 8; ++i) {
        int kk = k0 + i;
        v[i] = (kk < 195) ? (f16)W[kk * O + o] : (f16)0.f;
    }
    *(f16x8*)&Wf[(size_t)u * 8] = v;
}

// ---------------- update Bf x-columns (p=0): from x[b,0,:,0] (prologue only) -----------------
__global__ __launch_bounds__(256) void upd_x(const float* __restrict__ x, int t,
                                             f16* __restrict__ Bf) {
    int idx = blockIdx.x * 256 + threadIdx.x;  // R = b*512+n
    if (idx >= RTOT) return;
    int b = idx >> 9, n = idx & 511;
    float v = x[((size_t)b * TT + t) * NN + n];
    Bf[bf_addr(n, b * DIN)] = (f16)v;
}

// ---------------- big MFMA GEMM: S_t = (Af @ Bf) stored as f16 [(b,n)][k*65+p], stride 256 ----
// 64x128 tile, BK=64, 4 waves (2x2), wave = 32x64 = 2x4 frags of 16x16x32.
// grid (17, 24) = 408 blocks, LDS 48 KB -> 3 blocks/CU.
__global__ __launch_bounds__(256) void mm_f16(const f16* __restrict__ Af,
                                              const f16* __restrict__ Bf,
                                              f16* __restrict__ St) {
    __shared__ f16 lds[2][12288];  // per buf: A 4096 f16 (8 subtiles) | B 8192 f16 (16 subtiles)
    int tid = threadIdx.x, wave = tid >> 6, lane = tid & 63;
    int wr = wave & 1, wc = wave >> 1;
    int nb = blockIdx.x, mb = blockIdx.y;
    f32x4 acc[2][4] = {};

#define STG(d, it)                                                                             \
    do {                                                                                       \
        _Pragma("unroll") for (int q6 = 0; q6 < 6; ++q6) {                                     \
            int q = q6 * 4 + wave;                                                             \
            if (q < 8) {                                                                       \
                int ksl = q >> 2, sub = q & 3;                                                 \
                GLD_LDS16(&Af[((size_t)(((it)*2 + ksl) * MSUB + mb * 4 + sub) * 64 + lane) * 8], \
                          &lds[d][q * 512 + lane * 8]);                                        \
            } else {                                                                           \
                int qb = q - 8, ksl = qb >> 3, sub = qb & 7;                                   \
                GLD_LDS16(&Bf[((size_t)(((it)*2 + ksl) * NSUB + nb * 8 + sub) * 64 + lane) * 8], \
                          &lds[d][4096 + qb * 512 + lane * 8]);                                \
            }                                                                                  \
        }                                                                                      \
    } while (0)

    STG(0, 0);
#pragma unroll 1
    for (int it = 0; it < 8; ++it) {
        int d = it & 1;
        __syncthreads();
        if (it + 1 < 8) STG(d ^ 1, it + 1);
#pragma unroll
        for (int kk = 0; kk < 2; ++kk) {
            f16x8 a[2], b[4];
#pragma unroll
            for (int i = 0; i < 2; ++i) a[i] = *(const f16x8*)&lds[d][(kk * 4 + wr * 2 + i) * 512 + lane * 8];
#pragma unroll
            for (int j = 0; j < 4; ++j) b[j] = *(const f16x8*)&lds[d][4096 + (kk * 8 + wc * 4 + j) * 512 + lane * 8];
#pragma unroll
            for (int i = 0; i < 2; ++i)
#pragma unroll
                for (int j = 0; j < 4; ++j)
                    acc[i][j] = __builtin_amdgcn_mfma_f32_16x16x32_f16(a[i], b[j], acc[i][j], 0, 0, 0);
        }
    }
#undef STG

    // epilogue: element (m, c) -> S_t[(b*512+n)*256 + k*65+p] f16
    int k = mb >> 3;  // 64-row blocks: 8 per k-layer
    int col = lane & 15;
#pragma unroll
    for (int j = 0; j < 4; ++j) {
        int c = nb * 128 + (wc * 4 + j) * 16 + col;
        if (c < BD) {
            int b = c / DIN, p = c - b * DIN;
            size_t base = (size_t)(b * 512) * 256 + k * DIN + p;
#pragma unroll
            for (int i = 0; i < 2; ++i) {
                int n0 = (mb * 4 + wr * 2 + i) * 16 + (lane >> 4) * 4 - k * 512;
#pragma unroll
                for (int rI = 0; rI < 4; ++rI)
                    St[base + (size_t)(n0 + rI) * 256] = (f16)acc[i][j][rI];
            }
        }
    }
}

// ---------------- gates dense: zr = sigmoid(S_t @ Wg + bg); z->zf frags, r*h -> Bf ------------
// M=16384, N=128, K=224. Block: 64 rows, 4 waves 2x2, wave = 32R x 64o.
__global__ __launch_bounds__(256) void dense_gates(const f16* __restrict__ St,
                                                   const f16* __restrict__ Wf,
                                                   const float* __restrict__ bias,
                                                   const float* __restrict__ hf,
                                                   float* __restrict__ zf,
                                                   f16* __restrict__ Bf) {
    int tid = threadIdx.x, wave = tid >> 6, lane = tid & 63;
    int wr = wave & 1, wc = wave >> 1;
    int R0 = blockIdx.x * 64 + wr * 32;

    f16x8 af[7][2];
    const f16* Sb = St + (size_t)(R0 + (lane & 15)) * 256 + (lane >> 4) * 8;
#pragma unroll
    for (int ks = 0; ks < 7; ++ks)
#pragma unroll
        for (int rs = 0; rs < 2; ++rs)
            af[ks][rs] = *(const f16x8*)&Sb[(size_t)rs * 16 * 256 + ks * 32];

    f32x4 acc[2][4] = {};
#pragma unroll
    for (int ks = 0; ks < 7; ++ks)
#pragma unroll
        for (int os = 0; os < 4; ++os) {
            f16x8 w = *(const f16x8*)&Wf[((size_t)(ks * 8 + wc * 4 + os) * 64 + lane) * 8];
#pragma unroll
            for (int rs = 0; rs < 2; ++rs)
                acc[rs][os] = __builtin_amdgcn_mfma_f32_16x16x32_f16(af[ks][rs], w, acc[rs][os], 0, 0, 0);
        }

    int col = lane & 15;
#pragma unroll
    for (int rs = 0; rs < 2; ++rs) {
        int rf = (R0 >> 4) + rs;
#pragma unroll
        for (int os = 0; os < 4; ++os) {
            int o = wc * 64 + os * 16 + col;
            float bs = bias[o];
            if (wc == 0) {
                f32x4 v;
#pragma unroll
                for (int rI = 0; rI < 4; ++rI) v[rI] = 1.f / (1.f + expf(-(acc[rs][os][rI] + bs)));
                *(f32x4*)&zf[((size_t)(rf * 4 + os) * 64 + lane) * 4] = v;
            } else {
                int oh = o - 64;
                f32x4 hv = *(const f32x4*)&hf[((size_t)(rf * 4 + os) * 64 + lane) * 4];
#pragma unroll
                for (int rI = 0; rI < 4; ++rI) {
                    float rr = 1.f / (1.f + expf(-(acc[rs][os][rI] + bs)));
                    int R = rf * 16 + (lane >> 4) * 4 + rI;
                    int n = R & 511, b = R >> 9;
                    Bf[bf_addr(n, b * DIN + 1 + oh)] = (f16)(rr * hv[rI]);
                }
            }
        }
    }
}

// ------- candidate dense + GRU update + fused tail (encoder: next-x write; decoder: proj) -----
// h = (1-z)h + z*tanh(S_t @ Wu + bu). Block: 64 rows, 4 waves 2x2, wave = 32R x 32o.
// mode 0 (encoder): tail writes Bf x-col = xnext[b,tnext,n] (or 0 if xnext==null).
// mode 1 (decoder): tail computes go = h @ Wp + bp, writes out[b,t,n] and Bf x-col.
__global__ __launch_bounds__(256) void dense_cand(const f16* __restrict__ St,
                                                  const f16* __restrict__ Wf,
                                                  const float* __restrict__ bias,
                                                  const float* __restrict__ zf,
                                                  float* __restrict__ hf,
                                                  f16* __restrict__ Bf,
                                                  const float* __restrict__ xnext, int tnext,
                                                  const float* __restrict__ Wp,
                                                  const float* __restrict__ bp,
                                                  float* __restrict__ outp, int t, int hor,
                                                  int mode) {
    __shared__ float pls[2][64][16];  // [wc][row-in-block][col-lane] proj partials
    int tid = threadIdx.x, wave = tid >> 6, lane = tid & 63;
    int wr = wave & 1, wc = wave >> 1;
    int R0 = blockIdx.x * 64 + wr * 32;

    f16x8 af[7][2];
    const f16* Sb = St + (size_t)(R0 + (lane & 15)) * 256 + (lane >> 4) * 8;
#pragma unroll
    for (int ks = 0; ks < 7; ++ks)
#pragma unroll
        for (int rs = 0; rs < 2; ++rs)
            af[ks][rs] = *(const f16x8*)&Sb[(size_t)rs * 16 * 256 + ks * 32];

    f32x4 acc[2][2] = {};
#pragma unroll
    for (int ks = 0; ks < 7; ++ks)
#pragma unroll
        for (int os = 0; os < 2; ++os) {
            f16x8 w = *(const f16x8*)&Wf[((size_t)(ks * 4 + wc * 2 + os) * 64 + lane) * 8];
#pragma unroll
            for (int rs = 0; rs < 2; ++rs)
                acc[rs][os] = __builtin_amdgcn_mfma_f32_16x16x32_f16(af[ks][rs], w, acc[rs][os], 0, 0, 0);
        }

    int col = lane & 15;
    float pp[2][4] = {};  // [rs][rI] proj partial over this wave's o columns
#pragma unroll
    for (int rs = 0; rs < 2; ++rs) {
        int rf = (R0 >> 4) + rs;
#pragma unroll
        for (int os = 0; os < 2; ++os) {
            int o = wc * 32 + os * 16 + col;
            int of = wc * 2 + os;
            float bs = bias[o];
            float wp = (mode == 1) ? Wp[o] : 0.f;
            f32x4 zv = *(const f32x4*)&zf[((size_t)(rf * 4 + of) * 64 + lane) * 4];
            f32x4 hv = *(const f32x4*)&hf[((size_t)(rf * 4 + of) * 64 + lane) * 4];
            f32x4 hn;
#pragma unroll
            for (int rI = 0; rI < 4; ++rI) {
                float hc = tanhf(acc[rs][os][rI] + bs);
                hn[rI] = (1.f - zv[rI]) * hv[rI] + zv[rI] * hc;
                pp[rs][rI] += hn[rI] * wp;
            }
            *(f32x4*)&hf[((size_t)(rf * 4 + of) * 64 + lane) * 4] = hn;
#pragma unroll
            for (int rI = 0; rI < 4; ++rI) {
                int R = rf * 16 + (lane >> 4) * 4 + rI;
                int n = R & 511, b = R >> 9;
                Bf[bf_addr(n, b * DIN + 1 + o)] = (f16)hn[rI];
            }
        }
    }
    if (mode == 1) {
#pragma unroll
        for (int rs = 0; rs < 2; ++rs)
#pragma unroll
            for (int rI = 0; rI < 4; ++rI)
                pls[wc][wr * 32 + rs * 16 + (lane >> 4) * 4 + rI][col] = pp[rs][rI];
    }
    __syncthreads();
    if (tid < 64) {
        int rb = tid;
        int R = blockIdx.x * 64 + rb;
        int n = R & 511, b = R >> 9;
        if (mode == 1) {
            float v = bp[0];
#pragma unroll
            for (int cc = 0; cc < 16; ++cc) v += pls[0][rb][cc] + pls[1][rb][cc];
            outp[((size_t)b * hor + t) * NN + n] = v;
            Bf[bf_addr(n, b * DIN)] = (f16)v;
        } else {
            float v = xnext ? xnext[((size_t)b * TT + tnext) * NN + n] : 0.f;
            Bf[bf_addr(n, b * DIN)] = (f16)v;
        }
    }
}

extern "C" void kernel_launch(void* const* d_in, const int* in_sizes, int n_in,
                              void* d_out, int out_size, void* d_ws, size_t ws_size,
                              hipStream_t stream) {
    const float* x   = (const float*)d_in[0];
    const float* P   = (const float*)d_in[1];
    const float* Weg = (const float*)d_in[2];
    const float* beg = (const float*)d_in[3];
    const float* Weu = (const float*)d_in[4];
    const float* beu = (const float*)d_in[5];
    const float* Wdg = (const float*)d_in[6];
    const float* bdg = (const float*)d_in[7];
    const float* Wdu = (const float*)d_in[8];
    const float* bdu = (const float*)d_in[9];
    const float* Wp  = (const float*)d_in[10];
    const float* bp  = (const float*)d_in[11];
    float* out = (float*)d_out;
    int hor = out_size / (BB * NN);

    float* ws = (float*)d_ws;
    size_t off = 0;
    float* hf = ws + off; off += (size_t)RTOT * HH;                 // frag-major h (4 MB)
    float* zf = ws + off; off += (size_t)RTOT * HH;                 // frag-major z (4 MB)
    f16* St   = (f16*)(ws + off); off += (size_t)RTOT * 256 / 2;    // S_t f16 [16384][256]
    f16* Bf   = (f16*)(ws + off); off += (size_t)512 * BDP / 2;     // B frag-major
    f16* Af   = (f16*)(ws + off); off += (size_t)ROWS * 512 / 2;    // A frag-major
    f16* Wfeg = (f16*)(ws + off); off += 7 * 8 * 64 * 8 / 2;
    f16* Wfeu = (f16*)(ws + off); off += 7 * 4 * 64 * 8 / 2;
    f16* Wfdg = (f16*)(ws + off); off += 7 * 8 * 64 * 8 / 2;
    f16* Wfdu = (f16*)(ws + off); off += 7 * 4 * 64 * 8 / 2;

    hipMemsetAsync(hf, 0, (size_t)RTOT * HH * sizeof(float), stream);
    hipMemsetAsync(Bf, 0, (size_t)512 * BDP * sizeof(f16), stream);
    hipMemsetAsync(St, 0, (size_t)RTOT * 256 * sizeof(f16), stream);  // k-pad cols must be finite

    conv_a<<<(ROWS * 512 / 8) / 256, 256, 0, stream>>>(P, Af);
    conv_w<<<14, 256, 0, stream>>>(Weg, 128, 8, Wfeg);
    conv_w<<<7,  256, 0, stream>>>(Weu, 64, 4, Wfeu);
    conv_w<<<14, 256, 0, stream>>>(Wdg, 128, 8, Wfdg);
    conv_w<<<7,  256, 0, stream>>>(Wdu, 64, 4, Wfdu);
    upd_x<<<RTOT / 256, 256, 0, stream>>>(x, 0, Bf);

    dim3 mmgrid(BDP / 128, ROWS / 64);  // 17 x 24

    for (int t = 0; t < TT; ++t) {
        mm_f16<<<mmgrid, 256, 0, stream>>>(Af, Bf, St);
        dense_gates<<<RTOT / 64, 256, 0, stream>>>(St, Wfeg, beg, hf, zf, Bf);
        mm_f16<<<mmgrid, 256, 0, stream>>>(Af, Bf, St);
        dense_cand<<<RTOT / 64, 256, 0, stream>>>(St, Wfeu, beu, zf, hf, Bf,
                                                  (t + 1 < TT) ? x : nullptr, t + 1,
                                                  nullptr, nullptr, nullptr, 0, hor, 0);
    }
    for (int t = 0; t < hor; ++t) {
        mm_f16<<<mmgrid, 256, 0, stream>>>(Af, Bf, St);
        dense_gates<<<RTOT / 64, 256, 0, stream>>>(St, Wfdg, bdg, hf, zf, Bf);
        mm_f16<<<mmgrid, 256, 0, stream>>>(Af, Bf, St);
        dense_cand<<<RTOT / 64, 256, 0, stream>>>(St, Wfdu, bdu, zf, hf, Bf,
                                                  nullptr, 0,
                                                  Wp, bp, out, t, hor, 1);
    }
}